// Round 23
// baseline (150.476 us; speedup 1.0000x reference)
//
#include <hip/hip_runtime.h>
#include <hip/hip_bf16.h>
#include <stdint.h>

// GatheringLoss: score = q[32768x512] @ items[4096x512]^T, idx = argmax_row,
// out = mean((q - items[idx])^2).
// R23: TLP doubling. Seven null ILP levers at 2 waves/SIMD say the residual
// is wait that only MORE WAVES can hide. BM=64, grid=512, 2 blocks/CU ->
// 4 waves/SIMD, forced by __launch_bounds__(512,4) (budget ~110 regs:
// acc[1][2]=32 + av 8 + bv 16 + rmax/rid 32 + addr). Single-buffered frags
// (dbuf was null). Same float argmax fold/butterfly narrowed to fr=0; same
// C/D row formula; sV/sI [4][64]; MSE 8 rows/wave; final_reduce sums 512.
// pk2 layout + pitch-528 A LDS from R20/R21 (validated absmax 0.0).
// ws: [0,2MB) pk2 fp8 packed items | [+4MB) ihl fp16 items | [+2KB) partials

#define D_DIM 512
#define M_ITEMS 4096
#define N_ROWS 32768
#define BM 64
#define GCOLS 512            // cols per group
#define NG (M_ITEMS / GCOLS) // 8 groups
#define APITCH 528           // A LDS row pitch (512 + 16B pad)
#define NIT 128              // 8 g x 2 half x 8 kc64

typedef _Float16 half8 __attribute__((ext_vector_type(8)));
typedef _Float16 half4h __attribute__((ext_vector_type(4)));
typedef float f32x16 __attribute__((ext_vector_type(16)));
typedef float f32x4v __attribute__((ext_vector_type(4)));
typedef int i32x8 __attribute__((ext_vector_type(8)));

__device__ inline unsigned pack4_fp8(float a, float b, float c, float d) {
  int v = 0;
  v = __builtin_amdgcn_cvt_pk_fp8_f32(a, b, v, false); // bytes 0,1
  v = __builtin_amdgcn_cvt_pk_fp8_f32(c, d, v, true);  // bytes 2,3
  return (unsigned)v;
}

__global__ __launch_bounds__(256) void cast_f32_f16(
    const float* __restrict__ in, _Float16* __restrict__ out, int n4) {
  const int stride = gridDim.x * blockDim.x;
  for (int i = blockIdx.x * blockDim.x + threadIdx.x; i < n4; i += stride) {
    const f32x4v v = reinterpret_cast<const f32x4v*>(in)[i];
    half4h h;
    h.x = (_Float16)v.x;
    h.y = (_Float16)v.y;
    h.z = (_Float16)v.z;
    h.w = (_Float16)v.w;
    reinterpret_cast<half4h*>(out)[i] = h;
  }
}

// pk2[g][kc64][c][64]: 16B unit u -> q=u&3, c=(u>>2)&511, kc64=(u>>11)&7,
// g=u>>14. Holds items[g*512+c][kc64*64 + q*16 .. +16) as fp8.
__global__ __launch_bounds__(256) void pack_items_fp8(
    const float* __restrict__ itf, unsigned char* __restrict__ pk2) {
  const int u = blockIdx.x * blockDim.x + threadIdx.x; // 0..131071
  const int q = u & 3;
  const int c = (u >> 2) & 511;
  const int kc64 = (u >> 11) & 7;
  const int g = u >> 14;
  const int m = g * 512 + c;
  const float* src = itf + (size_t)m * D_DIM + kc64 * 64 + q * 16;
  const f32x4v a = *reinterpret_cast<const f32x4v*>(src);
  const f32x4v b = *reinterpret_cast<const f32x4v*>(src + 4);
  const f32x4v cc = *reinterpret_cast<const f32x4v*>(src + 8);
  const f32x4v d = *reinterpret_cast<const f32x4v*>(src + 12);
  uint4 o;
  o.x = pack4_fp8(a.x, a.y, a.z, a.w);
  o.y = pack4_fp8(b.x, b.y, b.z, b.w);
  o.z = pack4_fp8(cc.x, cc.y, cc.z, cc.w);
  o.w = pack4_fp8(d.x, d.y, d.z, d.w);
  *reinterpret_cast<uint4*>(pk2 + (size_t)u * 16) = o;
}

__global__ __launch_bounds__(512, 4) void score_mse(
    const float* __restrict__ qf, const unsigned char* __restrict__ pk2,
    const _Float16* __restrict__ ihl, float* __restrict__ partials) {
  __shared__ __align__(16) unsigned char Alds8[BM * APITCH]; // 33 KiB
  __shared__ float sV[4][BM];
  __shared__ int sI[4][BM];
  __shared__ float sSum[8];

  const int t = threadIdx.x; // 0..511
  const int lane = t & 63;
  const int wid = t >> 6;  // 0..7
  const int wm = wid >> 2; // 0..1 (row half: 32 rows)
  const int wn = wid & 3;  // 0..3 (col quarter: 128 cols)
  const int l31 = lane & 31;
  const int hsel = lane >> 5; // 0..1

  // T1: XCD chunking (grid 512 = 8 XCD x 64)
  const int bid = blockIdx.x;
  const int rb = (bid & 7) * 64 + (bid >> 3);
  const int row0 = rb * BM;

  // --- prologue: cast this block's 64 q rows f32->fp8 into Alds8 (linear
  // within row, pitch 528). 2048 16B-units, 4 per thread.
#pragma unroll
  for (int i = 0; i < 4; ++i) {
    const int f = i * 512 + t; // 0..2047
    const int r = f >> 5;
    const int u = f & 31;
    const float* src = qf + (size_t)(row0 + r) * D_DIM + u * 16;
    const f32x4v a = *(const f32x4v*)(src);
    const f32x4v b = *(const f32x4v*)(src + 4);
    const f32x4v c = *(const f32x4v*)(src + 8);
    const f32x4v d = *(const f32x4v*)(src + 12);
    uint4 o;
    o.x = pack4_fp8(a.x, a.y, a.z, a.w);
    o.y = pack4_fp8(b.x, b.y, b.z, b.w);
    o.z = pack4_fp8(c.x, c.y, c.z, c.w);
    o.w = pack4_fp8(d.x, d.y, d.z, d.w);
    *reinterpret_cast<uint4*>(Alds8 + (size_t)r * APITCH + u * 16) = o;
  }
  __syncthreads();

  f32x16 acc[2]; // [fc]: rows wm*32+l31(base row), cols +fc*32
#pragma unroll
  for (int fc = 0; fc < 2; ++fc) acc[fc] = (f32x16)(0.0f);
  float rmax[16];
  int rid[16];
#pragma unroll
  for (int rg = 0; rg < 16; ++rg) {
    rmax[rg] = -3.0e38f;
    rid[rg] = 0;
  }

  // Hoisted lane bases. A row = wm*32 + l31, k-half by hsel.
  const unsigned char* Aptr =
      Alds8 + (size_t)(wm * 32 + l31) * APITCH + hsel * 32;
  // B lane base: (wn*128 + l31)*64 + hsel*32.
  const unsigned char* pB = pk2 + ((size_t)(wn * 128 + l31) << 6) + hsel * 32;

#pragma unroll 1
  for (int n = 0; n < NIT; ++n) {
    const int g = n >> 4;
    const int half = (n >> 3) & 1;
    const int kc64 = n & 7;
    const unsigned char* p_ =
        pB + (((size_t)g << 18) + ((size_t)kc64 << 15) + ((size_t)half << 12));
    const i32x8 bv0 = *(const i32x8*)(p_);
    const i32x8 bv1 = *(const i32x8*)(p_ + 2048);
    const i32x8 av = *(const i32x8*)(Aptr + kc64 * 64);
    acc[0] = __builtin_amdgcn_mfma_scale_f32_32x32x64_f8f6f4(
        av, bv0, acc[0], 0, 0, 0, 127, 0, 127);
    acc[1] = __builtin_amdgcn_mfma_scale_f32_32x32x64_f8f6f4(
        av, bv1, acc[1], 0, 0, 0, 127, 0, 127);
    if ((n & 7) == 7) { // (g,half) complete: fold. cols ascend -> strict >
      const int colbase = g * GCOLS + half * 64 + wn * 128 + l31;
#pragma unroll
      for (int rg = 0; rg < 16; ++rg) {
        float v = acc[0][rg];
        int c = colbase;
        const float vv = acc[1][rg];
        if (vv > v) {
          v = vv;
          c = colbase + 32;
        }
        if (v > rmax[rg]) {
          rmax[rg] = v;
          rid[rg] = c;
        }
      }
#pragma unroll
      for (int fc = 0; fc < 2; ++fc) acc[fc] = (f32x16)(0.0f);
    }
  }

  // --- argmax block reduce. C/D layout (m74/m101): col = lane&31,
  // row = (rg&3) + 8*(rg>>2) + 4*(lane>>5). Butterfly over 32 col-lanes
  // (xor<32 stays within each hsel half, which owns its row).
#pragma unroll
  for (int rg = 0; rg < 16; ++rg) {
    float v = rmax[rg];
    int c = rid[rg];
#pragma unroll
    for (int m = 1; m < 32; m <<= 1) {
      const float ov = __shfl_xor(v, m, 64);
      const int oc = __shfl_xor(c, m, 64);
      if (ov > v || (ov == v && oc < c)) {
        v = ov;
        c = oc;
      }
    }
    if (l31 == rg) { // keeper in each hsel half
      const int row_local = wm * 32 + (rg & 3) + 8 * (rg >> 2) + 4 * hsel;
      sV[wn][row_local] = v;
      sI[wn][row_local] = c;
    }
  }
  __syncthreads();
  if (t < BM) {
    float fv = sV[0][t];
    int fi = sI[0][t];
#pragma unroll
    for (int w = 1; w < 4; ++w) {
      const float v = sV[w][t];
      const int ii = sI[w][t];
      if (v > fv || (v == fv && ii < fi)) {
        fv = v;
        fi = ii;
      }
    }
    sI[0][t] = fi; // merged winner per row
  }
  __syncthreads();

  // --- fused MSE epilogue: wave wid handles rows wid*8..+7.
  // q EXACT from global f32; gathered item from fp16 ihl.
  float lsum = 0.0f;
#pragma unroll 1
  for (int rr = 0; rr < 8; ++rr) {
    const int r = wid * 8 + rr;
    const int fi = sI[0][r];
    const float* qr = qf + (size_t)(row0 + r) * D_DIM + lane * 8;
    const f32x4v a0 = *(const f32x4v*)(qr);
    const f32x4v a1 = *(const f32x4v*)(qr + 4);
    const half8 ag = *(const half8*)(ihl + (size_t)fi * D_DIM + lane * 8);
    const float d0 = a0.x - (float)ag[0], d1 = a0.y - (float)ag[1];
    const float d2 = a0.z - (float)ag[2], d3 = a0.w - (float)ag[3];
    const float d4 = a1.x - (float)ag[4], d5 = a1.y - (float)ag[5];
    const float d6 = a1.z - (float)ag[6], d7 = a1.w - (float)ag[7];
    lsum += d0 * d0 + d1 * d1 + d2 * d2 + d3 * d3 + d4 * d4 + d5 * d5 +
            d6 * d6 + d7 * d7;
  }
#pragma unroll
  for (int m = 1; m < 64; m <<= 1) lsum += __shfl_xor(lsum, m, 64);
  if (lane == 0) sSum[wid] = lsum;
  __syncthreads();
  if (t == 0) {
    float s = 0.0f;
#pragma unroll
    for (int w = 0; w < 8; ++w) s += sSum[w];
    partials[bid] = s;
  }
}

__global__ __launch_bounds__(256) void final_reduce(
    const float* __restrict__ partials, float* __restrict__ out) {
  __shared__ float sS[4];
  const int t = threadIdx.x;
  float v = partials[t] + partials[t + 256]; // 512 partials
#pragma unroll
  for (int m = 1; m < 64; m <<= 1) v += __shfl_xor(v, m, 64);
  if ((t & 63) == 0) sS[t >> 6] = v;
  __syncthreads();
  if (t == 0)
    out[0] = (sS[0] + sS[1] + sS[2] + sS[3]) *
             (1.0f / ((float)N_ROWS * (float)D_DIM));
}

extern "C" void kernel_launch(void* const* d_in, const int* in_sizes, int n_in,
                              void* d_out, int out_size, void* d_ws,
                              size_t ws_size, hipStream_t stream) {
  const float* qf = (const float*)d_in[0];  // [32768][512]
  const float* itf = (const float*)d_in[1]; // [4096][512]
  char* ws = (char*)d_ws;
  unsigned char* pk2 = (unsigned char*)ws;                       // 2 MB fp8
  _Float16* ihl = (_Float16*)(ws + (size_t)M_ITEMS * D_DIM);     // 4 MB fp16
  float* partials =
      (float*)(ws + (size_t)M_ITEMS * D_DIM + (size_t)M_ITEMS * D_DIM * 2);
  float* out = (float*)d_out;

  cast_f32_f16<<<512, 256, 0, stream>>>(itf, ihl, M_ITEMS * D_DIM / 4);
  pack_items_fp8<<<512, 256, 0, stream>>>(itf, pk2);
  score_mse<<<N_ROWS / BM, 512, 0, stream>>>(qf, pk2, ihl, partials);
  final_reduce<<<1, 256, 0, stream>>>(partials, out);
}

// Round 24
// 112.167 us; speedup vs baseline: 1.3415x; 1.3415x over previous
//
#include <hip/hip_runtime.h>
#include <hip/hip_bf16.h>
#include <stdint.h>

// GatheringLoss: score = q[32768x512] @ items[4096x512]^T, idx = argmax_row,
// out = mean((q - items[idx])^2).
// R24: REVERT to R19 (best green: 111.8us total, absmax 0.0). R23 proved the
// TLP direction regresses (BM=64 doubles per-CU L1 B-traffic: 43% occupancy
// but MfmaUtil 25->18, 154us); R20-R22 proved addressing/pipelining levers
// are null at this operating point. R19 = the structure's measured optimum:
// MX-scaled fp8 (unit scales = exact fp8 math, 2x rate), 2M x 4N waves,
// BM=128, barrier-free loop, 64 K=64 iters, in-loop group fold, float
// argmax + butterfly + sV/sI merge, fused q-cast prologue + exact MSE.
// ws: [0,2MB) pk fp8 packed items | [+4MB) ihl fp16 items | [+1KB) partials

#define D_DIM 512
#define M_ITEMS 4096
#define N_ROWS 32768
#define BM 128
#define GCOLS 512            // cols per group
#define NG (M_ITEMS / GCOLS) // 8 groups
#define TOT64 64             // NG * 8 K=64 chunks

typedef _Float16 half8 __attribute__((ext_vector_type(8)));
typedef _Float16 half4h __attribute__((ext_vector_type(4)));
typedef float f32x16 __attribute__((ext_vector_type(16)));
typedef float f32x4v __attribute__((ext_vector_type(4)));
typedef int i32x8 __attribute__((ext_vector_type(8)));

__device__ inline unsigned pack4_fp8(float a, float b, float c, float d) {
  int v = 0;
  v = __builtin_amdgcn_cvt_pk_fp8_f32(a, b, v, false); // bytes 0,1
  v = __builtin_amdgcn_cvt_pk_fp8_f32(c, d, v, true);  // bytes 2,3
  return (unsigned)v;
}

__global__ __launch_bounds__(256) void cast_f32_f16(
    const float* __restrict__ in, _Float16* __restrict__ out, int n4) {
  const int stride = gridDim.x * blockDim.x;
  for (int i = blockIdx.x * blockDim.x + threadIdx.x; i < n4; i += stride) {
    const f32x4v v = reinterpret_cast<const f32x4v*>(in)[i];
    half4h h;
    h.x = (_Float16)v.x;
    h.y = (_Float16)v.y;
    h.z = (_Float16)v.z;
    h.w = (_Float16)v.w;
    reinterpret_cast<half4h*>(out)[i] = h;
  }
}

// pk[kc][m][16] fp8 bytes: unit u = kc*4096 + m holds items[m][kc*16..+16).
__global__ __launch_bounds__(256) void pack_items_fp8(
    const float* __restrict__ itf, unsigned char* __restrict__ pk) {
  const int u = blockIdx.x * blockDim.x + threadIdx.x; // 0..131071
  const int kc = u >> 12;
  const int m = u & 4095;
  const float* src = itf + (size_t)m * D_DIM + kc * 16;
  const f32x4v a = *reinterpret_cast<const f32x4v*>(src);
  const f32x4v b = *reinterpret_cast<const f32x4v*>(src + 4);
  const f32x4v c = *reinterpret_cast<const f32x4v*>(src + 8);
  const f32x4v d = *reinterpret_cast<const f32x4v*>(src + 12);
  uint4 o;
  o.x = pack4_fp8(a.x, a.y, a.z, a.w);
  o.y = pack4_fp8(b.x, b.y, b.z, b.w);
  o.z = pack4_fp8(c.x, c.y, c.z, c.w);
  o.w = pack4_fp8(d.x, d.y, d.z, d.w);
  *reinterpret_cast<uint4*>(pk + (size_t)u * 16) = o;
}

__global__ __launch_bounds__(512, 2) void score_mse(
    const float* __restrict__ qf, const unsigned char* __restrict__ pk,
    const _Float16* __restrict__ ihl, float* __restrict__ partials) {
  __shared__ __align__(16) unsigned char Alds8[BM * D_DIM]; // 64 KiB fp8 A
  __shared__ float sV[4][BM];
  __shared__ int sI[4][BM];
  __shared__ float sSum[8];

  const int t = threadIdx.x; // 0..511
  const int lane = t & 63;
  const int wid = t >> 6;  // 0..7
  const int wm = wid >> 2; // 0..1 (row half: 64 rows)
  const int wn = wid & 3;  // 0..3 (col quarter of 512: 128 cols)
  const int l31 = lane & 31;
  const int hsel = lane >> 5; // 0..1
  const int l7 = lane & 7;

  // T1: XCD chunking (grid 256 = 8 XCD x 32)
  const int bid = blockIdx.x;
  const int rb = (bid & 7) * 32 + (bid >> 3);
  const int row0 = rb * BM;

  // --- prologue: cast this block's 128 q rows f32->fp8 into Alds8, swizzled:
  // LDS 8B-unit (r,u) holds global k-unit u^(r&7) (8 elems).
#pragma unroll
  for (int i = 0; i < 16; ++i) {
    const int f = i * 512 + t; // 8192 units of 8B
    const int r = f >> 6;
    const int s = f & 63;
    const float* src = qf + (size_t)(row0 + r) * D_DIM + ((s ^ (r & 7)) * 8);
    const f32x4v a = *(const f32x4v*)(src);
    const f32x4v b = *(const f32x4v*)(src + 4);
    uint2 o;
    o.x = pack4_fp8(a.x, a.y, a.z, a.w);
    o.y = pack4_fp8(b.x, b.y, b.z, b.w);
    *reinterpret_cast<uint2*>(Alds8 + (size_t)f * 8) = o;
  }
  __syncthreads();

  f32x16 acc[2][4];
#pragma unroll
  for (int fr = 0; fr < 2; ++fr)
#pragma unroll
    for (int fc = 0; fc < 4; ++fc) acc[fr][fc] = (f32x16)(0.0f);
  float rmax[2][16];
  unsigned rid16[16]; // packed idx: bits [15:0]=fr0, [31:16]=fr1
#pragma unroll
  for (int rg = 0; rg < 16; ++rg) {
    rmax[0][rg] = -3.0e38f;
    rmax[1][rg] = -3.0e38f;
    rid16[rg] = 0u;
  }

  // A-frag row byte-offsets (row*512B); row&7 == l7 for both rows.
  const int arow0 = (wm * 64 + l31) * D_DIM;
  const int arow1 = (wm * 64 + 32 + l31) * D_DIM;

// A frag for K=64 chunk kc64 = J&7: global 8B-units u = kc64*8 + hsel*4 + j,
// j=0..3, LDS slot = u ^ l7 (row&7 == l7). k ascends across regs.
#define LOADA8(J, AROW, AV)                                                    \
  do {                                                                         \
    const int base_ = ((J) & 7) * 8 + hsel * 4;                                \
    const uint2 t0_ =                                                          \
        *(const uint2*)(Alds8 + (AROW) + (((base_ + 0) ^ l7) << 3));           \
    const uint2 t1_ =                                                          \
        *(const uint2*)(Alds8 + (AROW) + (((base_ + 1) ^ l7) << 3));           \
    const uint2 t2_ =                                                          \
        *(const uint2*)(Alds8 + (AROW) + (((base_ + 2) ^ l7) << 3));           \
    const uint2 t3_ =                                                          \
        *(const uint2*)(Alds8 + (AROW) + (((base_ + 3) ^ l7) << 3));           \
    AV = (i32x8){(int)t0_.x, (int)t0_.y, (int)t1_.x, (int)t1_.y,               \
                 (int)t2_.x, (int)t2_.y, (int)t3_.x, (int)t3_.y};              \
  } while (0)

// B frag: cols g*512 + wn*128 + FC*32 + l31; k-units kc16 = kc64*4 + hsel*2
// and +1 (two coalesced 16B loads 64KB apart). k ascends across regs.
#define LOADB8(J, FC, BV)                                                      \
  do {                                                                         \
    const int g_ = (J) >> 3, kc64_ = (J) & 7;                                  \
    const unsigned char* p_ =                                                  \
        pk + (((size_t)(kc64_ * 4 + hsel * 2) * 4096 + g_ * 512 + wn * 128 +   \
               (FC) * 32 + l31)                                                \
              << 4);                                                           \
    const uint4 b0_ = *(const uint4*)(p_);                                     \
    const uint4 b1_ = *(const uint4*)(p_ + (4096 << 4));                       \
    BV = (i32x8){(int)b0_.x, (int)b0_.y, (int)b0_.z, (int)b0_.w,               \
                 (int)b1_.x, (int)b1_.y, (int)b1_.z, (int)b1_.w};              \
  } while (0)

#pragma unroll 1
  for (int J = 0; J < TOT64; ++J) {
    i32x8 av0, av1;
    LOADA8(J, arow0, av0);
    LOADA8(J, arow1, av1);
#pragma unroll
    for (int fc = 0; fc < 4; ++fc) {
      i32x8 bv;
      LOADB8(J, fc, bv);
      // cbsz=0 (fp8 e4m3), blgp=0, scale opsel 0, scale byte 127 = x1.0
      acc[0][fc] = __builtin_amdgcn_mfma_scale_f32_32x32x64_f8f6f4(
          av0, bv, acc[0][fc], 0, 0, 0, 127, 0, 127);
      acc[1][fc] = __builtin_amdgcn_mfma_scale_f32_32x32x64_f8f6f4(
          av1, bv, acc[1][fc], 0, 0, 0, 127, 0, 127);
    }
    if ((J & 7) == 7) { // group complete: fold (trusted R16 code)
      const int colbase_ = (J >> 3) * GCOLS + wn * 128 + l31;
#pragma unroll
      for (int fr = 0; fr < 2; ++fr)
#pragma unroll
        for (int rg = 0; rg < 16; ++rg) {
          float v_ = acc[fr][0][rg];
          int c_ = colbase_;
#pragma unroll
          for (int fc = 1; fc < 4; ++fc) {
            const float vv_ = acc[fr][fc][rg];
            if (vv_ > v_) {
              v_ = vv_;
              c_ = colbase_ + fc * 32;
            }
          }
          if (v_ > rmax[fr][rg]) {
            rmax[fr][rg] = v_;
            rid16[rg] = (rid16[rg] & (fr ? 0x0000FFFFu : 0xFFFF0000u)) |
                        ((unsigned)c_ << (fr * 16));
          }
        }
#pragma unroll
      for (int fr = 0; fr < 2; ++fr)
#pragma unroll
        for (int fc = 0; fc < 4; ++fc) acc[fr][fc] = (f32x16)(0.0f);
    }
  }

  // --- argmax block reduce. C/D layout (m74/m101): col = lane&31,
  // row = (rg&3) + 8*(rg>>2) + 4*(lane>>5).
  float bv = -3.0e38f;
  int bi = 0;
#pragma unroll
  for (int fr = 0; fr < 2; ++fr)
#pragma unroll
    for (int rg = 0; rg < 16; ++rg) {
      float v = rmax[fr][rg];
      int c = (int)((rid16[rg] >> (fr * 16)) & 0xFFFFu);
#pragma unroll
      for (int m = 1; m < 32; m <<= 1) {
        const float ov = __shfl_xor(v, m, 64);
        const int oc = __shfl_xor(c, m, 64);
        if (ov > v || (ov == v && oc < c)) {
          v = ov;
          c = oc;
        }
      }
      if (l31 == fr * 16 + rg) {
        bv = v;
        bi = c;
      }
    }
  const int e = l31;
  const int row_local =
      wm * 64 + (e >> 4) * 32 + ((e & 3) + 8 * ((e >> 2) & 3)) + 4 * hsel;

  sV[wn][row_local] = bv;
  sI[wn][row_local] = bi;
  __syncthreads();
  if (t < BM) {
    float fv = sV[0][t];
    int fi = sI[0][t];
#pragma unroll
    for (int w = 1; w < 4; ++w) {
      const float v = sV[w][t];
      const int ii = sI[w][t];
      if (v > fv || (v == fv && ii < fi)) {
        fv = v;
        fi = ii;
      }
    }
    sI[0][t] = fi; // merged winner per row
  }
  __syncthreads();

  // --- fused MSE epilogue: wave wid handles rows wid*16..+15.
  // q EXACT from global f32; gathered item from fp16 ihl.
  float lsum = 0.0f;
#pragma unroll 1
  for (int rr = 0; rr < 16; ++rr) {
    const int r = wid * 16 + rr;
    const int fi = sI[0][r];
    const float* qr = qf + (size_t)(row0 + r) * D_DIM + lane * 8;
    const f32x4v a0 = *(const f32x4v*)(qr);
    const f32x4v a1 = *(const f32x4v*)(qr + 4);
    const half8 ag = *(const half8*)(ihl + (size_t)fi * D_DIM + lane * 8);
    const float d0 = a0.x - (float)ag[0], d1 = a0.y - (float)ag[1];
    const float d2 = a0.z - (float)ag[2], d3 = a0.w - (float)ag[3];
    const float d4 = a1.x - (float)ag[4], d5 = a1.y - (float)ag[5];
    const float d6 = a1.z - (float)ag[6], d7 = a1.w - (float)ag[7];
    lsum += d0 * d0 + d1 * d1 + d2 * d2 + d3 * d3 + d4 * d4 + d5 * d5 +
            d6 * d6 + d7 * d7;
  }
#pragma unroll
  for (int m = 1; m < 64; m <<= 1) lsum += __shfl_xor(lsum, m, 64);
  if (lane == 0) sSum[wid] = lsum;
  __syncthreads();
  if (t == 0) {
    float s = 0.0f;
#pragma unroll
    for (int w = 0; w < 8; ++w) s += sSum[w];
    partials[bid] = s;
  }
}

__global__ __launch_bounds__(256) void final_reduce(
    const float* __restrict__ partials, float* __restrict__ out) {
  __shared__ float sS[4];
  const int t = threadIdx.x;
  float v = partials[t]; // exactly 256 partials
#pragma unroll
  for (int m = 1; m < 64; m <<= 1) v += __shfl_xor(v, m, 64);
  if ((t & 63) == 0) sS[t >> 6] = v;
  __syncthreads();
  if (t == 0)
    out[0] = (sS[0] + sS[1] + sS[2] + sS[3]) *
             (1.0f / ((float)N_ROWS * (float)D_DIM));
}

extern "C" void kernel_launch(void* const* d_in, const int* in_sizes, int n_in,
                              void* d_out, int out_size, void* d_ws,
                              size_t ws_size, hipStream_t stream) {
  const float* qf = (const float*)d_in[0];  // [32768][512]
  const float* itf = (const float*)d_in[1]; // [4096][512]
  char* ws = (char*)d_ws;
  unsigned char* pk = (unsigned char*)ws;                        // 2 MB fp8
  _Float16* ihl = (_Float16*)(ws + (size_t)M_ITEMS * D_DIM);     // 4 MB fp16
  float* partials =
      (float*)(ws + (size_t)M_ITEMS * D_DIM + (size_t)M_ITEMS * D_DIM * 2);
  float* out = (float*)d_out;

  cast_f32_f16<<<512, 256, 0, stream>>>(itf, ihl, M_ITEMS * D_DIM / 4);
  pack_items_fp8<<<512, 256, 0, stream>>>(itf, pk);
  score_mse<<<N_ROWS / BM, 512, 0, stream>>>(qf, pk, ihl, partials);
  final_reduce<<<1, 256, 0, stream>>>(partials, out);
}